// Round 10
// baseline (236.197 us; speedup 1.0000x reference)
//
#include <hip/hip_runtime.h>
#include <hip/hip_fp16.h>

constexpr int N_NODES = 50000;
constexpr int N_EDGES = 800000;
constexpr int HIDDEN  = 128;
constexpr float RSQRT_D = 0.17677669529663687f;  // 1/sqrt(32)
constexpr int Y_SIZE = N_NODES * HIDDEN;         // 6,400,000
constexpr int M_PAD  = 50048;                    // 391 * 128
constexpr int SCAN_BLOCKS = 196;                 // 196*256 = 50176 >= N_NODES
constexpr int HIST_BLOCKS = N_EDGES / 256;       // 3125
constexpr int NORM_BLOCKS = (N_EDGES * 4) / 256; // 12500
constexpr int STAT_BLOCKS = (N_NODES + 31) / 32; // 1563

// ---- ws layout (float offsets) ----
constexpr size_t OFF_Q      = 0;         // fp16 qb (12.8 MB of 25.6 slot)
constexpr size_t OFF_K      = 6400000;   // fp16 kv interleaved [node][256]: 25.6 MB
constexpr size_t OFF_S      = 19200000;  // fp16 sb (lower half); exc (upper half)
constexpr size_t OFF_EXC    = 22400000;  // E*4 floats: CSR-ordered raw exp
constexpr size_t OFF_DENOM  = 25600000;  // N*4 floats; ALSO hosts Wt_swz (dead before k_fused)
constexpr size_t OFF_GSUM   = 25800000;  // 64
constexpr size_t OFF_GSQ    = 25800064;  // 64
constexpr size_t OFF_GCNT   = 25800128;  // 64 ints
constexpr size_t OFF_DEG    = 25800192;  // 50000 ints
constexpr size_t OFF_OFFS   = 25850192;  // 50001 ints
constexpr size_t OFF_CURSOR = 25900224;  // 50000 ints
constexpr size_t OFF_CSR    = 25950224;  // 800000 ints (csr_src)
constexpr size_t OFF_POS    = 26750224;  // 800000 ints (edge -> csr slot)
constexpr size_t OFF_PART   = 27550224;  // 196 ints (raw scan partials)

typedef __attribute__((ext_vector_type(8))) short bf16x8;
typedef __attribute__((ext_vector_type(4))) float f32x4;

__device__ __forceinline__ short f2bf(float f) {  // RNE f32 -> bf16 bits
    unsigned u = __float_as_uint(f);
    unsigned r = (u + 0x7fff + ((u >> 16) & 1)) >> 16;
    return (short)r;
}

__device__ __forceinline__ void gload_lds16(const void* g, void* l) {
    __builtin_amdgcn_global_load_lds(
        (const __attribute__((address_space(1))) void*)g,
        (__attribute__((address_space(3))) void*)l, 16, 0, 0);
}

// ---------------- prep: W->Wt bf16 swizzled | degree hist ----------------
__global__ __launch_bounds__(256) void k_prep(
    const float* __restrict__ Wq, const float* __restrict__ Wk,
    const float* __restrict__ Wv, const float* __restrict__ Wsm,
    const int* __restrict__ dst,
    short* __restrict__ wt, int* __restrict__ deg)
{
    int b = blockIdx.x;
    if (b < 32) {
        int tid = b * 256 + threadIdx.x;  // 8192 exact
        int mat = tid >> 11, n = (tid >> 4) & 127, kg = tid & 15;
        const float* W = (mat == 0) ? Wq : (mat == 1) ? Wk : (mat == 2) ? Wv : Wsm;
        short o[8];
        #pragma unroll
        for (int j = 0; j < 8; ++j) o[j] = f2bf(W[(kg * 8 + j) * 128 + n]);
        int cs = kg ^ (n & 7);
        *(int4*)&wt[mat * 16384 + n * 128 + cs * 8] = *(int4*)o;
    } else {
        int e = (b - 32) * 256 + threadIdx.x;  // E exact
        atomicAdd(&deg[dst[e]], 1);
    }
}

// ---------------- MFMA GEMM, single dispatch: all 4 mats per block ----------------
// A staged straight from f32 x (reg-staged cvt into swizzled bf16 LDS; no x_swz
// pass). B re-staged per mat via global_load_lds. All outputs fp16.
__global__ __launch_bounds__(256) void k_mm(
    const float* __restrict__ x, const short* __restrict__ wt,
    const float* __restrict__ bq, const float* __restrict__ bk,
    const float* __restrict__ bv, const float* __restrict__ bs,
    __half* __restrict__ qb, __half* __restrict__ kv, __half* __restrict__ sb)
{
    __shared__ __align__(16) char As[32768];
    __shared__ __align__(16) char Bs[32768];
    const int t = threadIdx.x, lane = t & 63, wv = t >> 6;
    const int m0 = blockIdx.x * 128;
    const int wm = wv >> 1, wn = wv & 1;

    // stage B (mat 0) async, stage A with f32->bf16 conversion
    #pragma unroll
    for (int i = 0; i < 8; ++i) {
        int chunk = wv * 8 + i;
        gload_lds16((const char*)wt + chunk * 1024 + lane * 16, Bs + chunk * 1024);
    }
    #pragma unroll
    for (int j = 0; j < 8; ++j) {
        int idx = t + 256 * j;            // 2048 chunks of 16B
        int row = idx >> 4, ci = idx & 15;
        int gr = m0 + row;
        short o[8];
        if (gr < N_NODES) {
            float4 a = *(const float4*)&x[(size_t)gr * 128 + ci * 8];
            float4 bb = *(const float4*)&x[(size_t)gr * 128 + ci * 8 + 4];
            o[0] = f2bf(a.x); o[1] = f2bf(a.y); o[2] = f2bf(a.z); o[3] = f2bf(a.w);
            o[4] = f2bf(bb.x); o[5] = f2bf(bb.y); o[6] = f2bf(bb.z); o[7] = f2bf(bb.w);
        } else {
            #pragma unroll
            for (int j2 = 0; j2 < 8; ++j2) o[j2] = 0;
        }
        int cs = ci ^ (row & 7);
        *(int4*)(As + row * 256 + cs * 16) = *(int4*)o;
    }
    __syncthreads();

    bf16x8 af[4][4];  // [ks][mf], same A for all mats
    #pragma unroll
    for (int ks = 0; ks < 4; ++ks) {
        const int cbase = ks * 64 + ((lane >> 4) << 4);
        #pragma unroll
        for (int mf = 0; mf < 4; ++mf) {
            int mr = wm * 64 + mf * 16 + (lane & 15);
            af[ks][mf] = *(const bf16x8*)(As + mr * 256 + (cbase ^ ((mr & 7) << 4)));
        }
    }

    const float* Bbs[4] = {bq, bk, bv, bs};
    #pragma unroll
    for (int mat = 0; mat < 4; ++mat) {
        f32x4 acc[4][4];
        #pragma unroll
        for (int nf = 0; nf < 4; ++nf) {
            float bc = Bbs[mat][wn * 64 + nf * 16 + (lane & 15)];
            #pragma unroll
            for (int mf = 0; mf < 4; ++mf) acc[mf][nf] = (f32x4){bc, bc, bc, bc};
        }
        #pragma unroll
        for (int ks = 0; ks < 4; ++ks) {
            bf16x8 bfr[4];
            const int cbase = ks * 64 + ((lane >> 4) << 4);
            #pragma unroll
            for (int nf = 0; nf < 4; ++nf) {
                int nc = wn * 64 + nf * 16 + (lane & 15);
                bfr[nf] = *(const bf16x8*)(Bs + nc * 256 + (cbase ^ ((nc & 7) << 4)));
            }
            #pragma unroll
            for (int mf = 0; mf < 4; ++mf)
                #pragma unroll
                for (int nf = 0; nf < 4; ++nf)
                    acc[mf][nf] = __builtin_amdgcn_mfma_f32_16x16x32_bf16(
                        af[ks][mf], bfr[nf], acc[mf][nf], 0, 0, 0);
        }
        __syncthreads();  // all waves done reading Bs
        if (mat < 3) {    // stage next mat's B while we write out
            const char* gB = (const char*)wt + (mat + 1) * 32768;
            #pragma unroll
            for (int i = 0; i < 8; ++i) {
                int chunk = wv * 8 + i;
                gload_lds16(gB + chunk * 1024 + lane * 16, Bs + chunk * 1024);
            }
        }
        __half* base = (mat == 0) ? qb : (mat == 1) ? kv : (mat == 2) ? (kv + 128) : sb;
        const int rs = (mat == 1 || mat == 2) ? 256 : 128;
        const int colbase = wn * 64 + (lane & 15);
        #pragma unroll
        for (int mf = 0; mf < 4; ++mf) {
            int rowb = m0 + wm * 64 + mf * 16 + ((lane >> 4) << 2);
            #pragma unroll
            for (int nf = 0; nf < 4; ++nf) {
                int col = colbase + nf * 16;
                #pragma unroll
                for (int r = 0; r < 4; ++r) {
                    int node = rowb + r;
                    if (node < N_NODES)
                        base[(size_t)node * rs + col] = __float2half_rn(acc[mf][nf][r]);
                }
            }
        }
        __syncthreads();  // staged Bs complete before next mat's reads
    }
}

// ---------------- scan: per-block sums, then fused partial-scan + intra ----------------
__global__ __launch_bounds__(256) void k_scan1(const int* __restrict__ deg,
                                               int* __restrict__ part)
{
    const int t = threadIdx.x;
    int idx = blockIdx.x * 256 + t;
    int v = (idx < N_NODES) ? deg[idx] : 0;
    #pragma unroll
    for (int o = 1; o < 64; o <<= 1) v += __shfl_xor(v, o);
    __shared__ int wsum[4];
    if ((t & 63) == 0) wsum[t >> 6] = v;
    __syncthreads();
    if (t == 0) part[blockIdx.x] = wsum[0] + wsum[1] + wsum[2] + wsum[3];
}

// scan3: each block redundantly scans the 196 raw partials (cheap), then
// intra-block exclusive scan -> offs/cursor. (scan2 launch folded in.)
__global__ __launch_bounds__(256) void k_scan3(const int* __restrict__ deg,
                                               const int* __restrict__ part,
                                               int* __restrict__ offs,
                                               int* __restrict__ cursor)
{
    __shared__ int pbuf[256];
    __shared__ int wsum[4];
    const int t = threadIdx.x;
    int pv = (t < SCAN_BLOCKS) ? part[t] : 0;
    pbuf[t] = pv;
    __syncthreads();
    for (int o = 1; o < 256; o <<= 1) {
        int tmp = (t >= o) ? pbuf[t - o] : 0;
        __syncthreads();
        pbuf[t] += tmp;
        __syncthreads();
    }
    const int bbase = (blockIdx.x == 0) ? 0 : pbuf[blockIdx.x - 1];

    const int idx = blockIdx.x * 256 + t;
    const int lane = t & 63, w = t >> 6;
    int v = (idx < N_NODES) ? deg[idx] : 0;
    int inc = v;
    #pragma unroll
    for (int o = 1; o < 64; o <<= 1) {
        int nb = __shfl_up(inc, o);
        if (lane >= o) inc += nb;
    }
    if (lane == 63) wsum[w] = inc;
    __syncthreads();
    int wbase = 0;
    #pragma unroll
    for (int i = 0; i < 4; ++i) if (i < w) wbase += wsum[i];
    int excl = bbase + wbase + inc - v;
    if (idx < N_NODES) {
        offs[idx] = excl;
        cursor[idx] = excl;
    }
    if (idx == 0) offs[N_NODES] = N_EDGES;
}

__global__ __launch_bounds__(256) void k_scatter(
    const int* __restrict__ src, const int* __restrict__ dst,
    int* __restrict__ cursor, int* __restrict__ csr_src, int* __restrict__ pos)
{
    int e = blockIdx.x * 256 + threadIdx.x;  // E exact
    int d = dst[e];
    int p = atomicAdd(&cursor[d], 1);
    csr_src[p] = src[e];
    pos[e] = p;  // sequential write; enables CSR-ordered exp store in k_fused
}

// ---------------- fused: logits + exp + denom + aggregate + skip ----------------
// One 64-lane wave per dst node; 16 lanes/edge (8 ch/lane), 4 edges per group.
// exp written SEQUENTIALLY at CSR slot (no random writes; k_post permutes).
__global__ __launch_bounds__(256) void k_fused(
    const __half* __restrict__ qb, const __half* __restrict__ kv,
    const __half* __restrict__ sb,
    const int* __restrict__ offs, const int* __restrict__ csr_src,
    float* __restrict__ exc, float* __restrict__ denom,
    float* __restrict__ outb)
{
    const int t = threadIdx.x;
    const int lane = t & 63;
    const int n = blockIdx.x * 4 + (t >> 6);  // grid*4 == N exact
    const int begin = offs[n], end = offs[n + 1];
    const int cl  = lane & 15;   // owns channels [cl*8, cl*8+8)
    const int qtr = lane >> 4;   // edge slot within 4-group
    const int h   = cl >> 2;     // head of this lane's channels

    const __half2* qp = (const __half2*)(qb + (size_t)n * 128 + cl * 8);
    float2 qf[4];
    #pragma unroll
    for (int j = 0; j < 4; ++j) qf[j] = __half22float2(qp[j]);

    float acc[8] = {0.f, 0.f, 0.f, 0.f, 0.f, 0.f, 0.f, 0.f};
    float dsum = 0.f;
    int i = begin;
    for (; i + 8 <= end; i += 8) {  // two 4-edge groups, unguarded
        const int s0 = csr_src[i + qtr];
        const int s1 = csr_src[i + 4 + qtr];
        const __half2* k0 = (const __half2*)(kv + (size_t)s0 * 256 + cl * 8);
        const __half2* k1 = (const __half2*)(kv + (size_t)s1 * 256 + cl * 8);
        __half2 ka[4], kb2[4], va[4], vb2[4];
        #pragma unroll
        for (int j = 0; j < 4; ++j) { ka[j] = k0[j]; va[j] = k0[64 + j]; }
        #pragma unroll
        for (int j = 0; j < 4; ++j) { kb2[j] = k1[j]; vb2[j] = k1[64 + j]; }
        float p0 = 0.f, p1 = 0.f;
        #pragma unroll
        for (int j = 0; j < 4; ++j) {
            float2 f0 = __half22float2(ka[j]), f1 = __half22float2(kb2[j]);
            p0 += qf[j].x * f0.x + qf[j].y * f0.y;
            p1 += qf[j].x * f1.x + qf[j].y * f1.y;
        }
        p0 += __shfl_xor(p0, 1);  p1 += __shfl_xor(p1, 1);
        p0 += __shfl_xor(p0, 2);  p1 += __shfl_xor(p1, 2);
        const float ex0 = __expf(p0 * RSQRT_D);
        const float ex1 = __expf(p1 * RSQRT_D);
        dsum += ex0 + ex1;
        #pragma unroll
        for (int j = 0; j < 4; ++j) {
            float2 f0 = __half22float2(va[j]), f1 = __half22float2(vb2[j]);
            acc[2*j]   += ex0 * f0.x + ex1 * f1.x;
            acc[2*j+1] += ex0 * f0.y + ex1 * f1.y;
        }
        if ((lane & 3) == 0) {
            exc[(i + qtr) * 4 + h]     = ex0;
            exc[(i + 4 + qtr) * 4 + h] = ex1;
        }
    }
    for (; i < end; i += 4) {  // guarded 4-edge tail
        const int eIdx = i + qtr;
        const bool act = eIdx < end;
        const int s0 = csr_src[act ? eIdx : end - 1];
        const __half2* k0 = (const __half2*)(kv + (size_t)s0 * 256 + cl * 8);
        __half2 ka[4], va[4];
        #pragma unroll
        for (int j = 0; j < 4; ++j) { ka[j] = k0[j]; va[j] = k0[64 + j]; }
        float p0 = 0.f;
        #pragma unroll
        for (int j = 0; j < 4; ++j) {
            float2 f0 = __half22float2(ka[j]);
            p0 += qf[j].x * f0.x + qf[j].y * f0.y;
        }
        p0 += __shfl_xor(p0, 1);
        p0 += __shfl_xor(p0, 2);
        const float ex0 = act ? __expf(p0 * RSQRT_D) : 0.f;
        dsum += ex0;
        #pragma unroll
        for (int j = 0; j < 4; ++j) {
            float2 f0 = __half22float2(va[j]);
            acc[2*j]   += ex0 * f0.x;
            acc[2*j+1] += ex0 * f0.y;
        }
        if (((lane & 3) == 0) && act) exc[eIdx * 4 + h] = ex0;
    }
    // combine the 4 edge-quarters (lanes l, l+16, l+32, l+48 share channels)
    dsum += __shfl_xor(dsum, 16);
    dsum += __shfl_xor(dsum, 32);
    #pragma unroll
    for (int j = 0; j < 8; ++j) {
        acc[j] += __shfl_xor(acc[j], 16);
        acc[j] += __shfl_xor(acc[j], 32);
    }
    if (lane < 16) {
        if ((lane & 3) == 0) denom[n * 4 + h] = dsum;
        const float rdn = 1.f / (dsum + 1e-16f);
        const __half2* sp = (const __half2*)(sb + (size_t)n * 128 + cl * 8);
        float o[8];
        #pragma unroll
        for (int j = 0; j < 4; ++j) {
            float2 sf = __half22float2(sp[j]);
            o[2*j]   = acc[2*j]   * rdn + sf.x;
            o[2*j+1] = acc[2*j+1] * rdn + sf.y;
        }
        *(float4*)&outb[(size_t)n * 128 + cl * 8]     = make_float4(o[0], o[1], o[2], o[3]);
        *(float4*)&outb[(size_t)n * 128 + cl * 8 + 4] = make_float4(o[4], o[5], o[6], o[7]);
    }
}

// ---------------- merged: attn permute+normalize | per-graph stats ----------------
__global__ __launch_bounds__(256) void k_post(
    float* __restrict__ attn, const float* __restrict__ exc,
    const int* __restrict__ pos, const float* __restrict__ denom,
    const int* __restrict__ dst,
    const float* __restrict__ out, const int* __restrict__ batch,
    float* __restrict__ gsum, float* __restrict__ gsq, int* __restrict__ gcnt)
{
    const int b = blockIdx.x;
    if (b < NORM_BLOCKS) {
        int idx = b * 256 + threadIdx.x;  // E*4 exact
        int e = idx >> 2, h = idx & 3;
        int p = pos[e];
        attn[idx] = exc[p * 4 + h] / (denom[dst[e] * 4 + h] + 1e-16f);
        return;
    }
    __shared__ float nsum[32], nsq[32];
    __shared__ int   ngr[32];
    const int t = threadIdx.x;
    const int nl = t >> 3, part = t & 7;
    const int n = (b - NORM_BLOCKS) * 32 + nl;
    float lsum = 0.f, lsq = 0.f;
    if (n < N_NODES) {
        size_t base = (size_t)n * 128 + part * 16;
        #pragma unroll
        for (int i = 0; i < 4; ++i) {
            float4 o = *(const float4*)&out[base + i * 4];
            lsum += o.x + o.y + o.z + o.w;
            lsq  += o.x * o.x + o.y * o.y + o.z * o.z + o.w * o.w;
        }
    }
    #pragma unroll
    for (int o = 1; o < 8; o <<= 1) {
        lsum += __shfl_xor(lsum, o);
        lsq  += __shfl_xor(lsq, o);
    }
    if (part == 0) { nsum[nl] = lsum; nsq[nl] = lsq; ngr[nl] = (n < N_NODES) ? batch[n] : -1; }
    __syncthreads();
    if (t == 0) {
        float acc = 0.f, accq = 0.f; int cg = ngr[0], cnt = 0;
        for (int i = 0; i < 32; ++i) {
            int g = ngr[i];
            if (g != cg) {
                if (cg >= 0) { atomicAdd(&gsum[cg], acc); atomicAdd(&gsq[cg], accq);
                               atomicAdd(&gcnt[cg], cnt); }
                acc = 0.f; accq = 0.f; cnt = 0; cg = g;
            }
            acc += nsum[i]; accq += nsq[i]; ++cnt;
        }
        if (cg >= 0) { atomicAdd(&gsum[cg], acc); atomicAdd(&gsq[cg], accq);
                       atomicAdd(&gcnt[cg], cnt); }
    }
}

// ---------------- LayerNorm affine + LeakyReLU (in-place) ----------------
__global__ __launch_bounds__(256) void k_final(
    const float* __restrict__ out, const int* __restrict__ batch,
    const float* __restrict__ gsum, const float* __restrict__ gsq,
    const int* __restrict__ gcnt,
    const float* __restrict__ lnw, const float* __restrict__ lnb,
    float* __restrict__ y)
{
    int idx = blockIdx.x * 256 + threadIdx.x;  // N*128 exact
    int n = idx >> 7, c = idx & 127;
    int g = batch[n];
    float norm = fmaxf((float)gcnt[g], 1.f) * 128.f;
    float mean = gsum[g] / norm;
    float var  = gsq[g] / norm - mean * mean;
    float inv  = rsqrtf(var + 1e-5f);
    float val  = (out[idx] - mean) * inv * lnw[c] + lnb[c];
    y[idx] = val > 0.f ? val : 0.01f * val;
}

extern "C" void kernel_launch(void* const* d_in, const int* in_sizes, int n_in,
                              void* d_out, int out_size, void* d_ws, size_t ws_size,
                              hipStream_t stream)
{
    (void)in_sizes; (void)n_in; (void)out_size; (void)ws_size;
    const float* x    = (const float*)d_in[0];
    const int*   ei   = (const int*)  d_in[1];
    const int*   batch= (const int*)  d_in[2];
    const float* Wq   = (const float*)d_in[3];
    const float* bq   = (const float*)d_in[4];
    const float* Wk   = (const float*)d_in[5];
    const float* bk   = (const float*)d_in[6];
    const float* Wv   = (const float*)d_in[7];
    const float* bv   = (const float*)d_in[8];
    const float* Wsm  = (const float*)d_in[9];
    const float* bs   = (const float*)d_in[10];
    const float* lnw  = (const float*)d_in[11];
    const float* lnb  = (const float*)d_in[12];

    float* outp = (float*)d_out;
    float* ws   = (float*)d_ws;

    const int* srcI = ei;
    const int* dstI = ei + N_EDGES;

    __half* qb      = (__half*)(ws + OFF_Q);
    __half* kv      = (__half*)(ws + OFF_K);
    __half* sb      = (__half*)(ws + OFF_S);
    float*  exc     = ws + OFF_EXC;
    float*  denom   = ws + OFF_DENOM;
    short*  wt      = (short*)(ws + OFF_DENOM);  // dead before k_fused writes denom
    float*  gsum    = ws + OFF_GSUM;
    float*  gsq     = ws + OFF_GSQ;
    int*    gcnt    = (int*)(ws + OFF_GCNT);
    int*    deg     = (int*)(ws + OFF_DEG);
    int*    offs    = (int*)(ws + OFF_OFFS);
    int*    cursor  = (int*)(ws + OFF_CURSOR);
    int*    csr_src = (int*)(ws + OFF_CSR);
    int*    pos     = (int*)(ws + OFF_POS);
    int*    partArr = (int*)(ws + OFF_PART);

    float* outb = outp;                   // y region doubles as pre-LN buffer
    float* attn = outp + Y_SIZE;

    // zero gsum/gsq/gcnt + deg (contiguous)
    hipMemsetAsync(gsum, 0, (size_t)(192 + N_NODES) * sizeof(float), stream);

    k_prep<<<32 + HIST_BLOCKS, 256, 0, stream>>>(Wq, Wk, Wv, Wsm, dstI, wt, deg);
    k_mm<<<M_PAD / 128, 256, 0, stream>>>(x, wt, bq, bk, bv, bs, qb, kv, sb);

    k_scan1<<<SCAN_BLOCKS, 256, 0, stream>>>(deg, partArr);
    k_scan3<<<SCAN_BLOCKS, 256, 0, stream>>>(deg, partArr, offs, cursor);
    k_scatter<<<N_EDGES / 256, 256, 0, stream>>>(srcI, dstI, cursor, csr_src, pos);
    k_fused<<<N_NODES / 4, 256, 0, stream>>>(qb, kv, sb, offs, csr_src,
                                             exc, denom, outb);
    k_post<<<NORM_BLOCKS + STAT_BLOCKS, 256, 0, stream>>>(
        attn, exc, pos, denom, dstI, outb, batch, gsum, gsq, gcnt);
    k_final<<<Y_SIZE / 256, 256, 0, stream>>>(outb, batch, gsum, gsq, gcnt,
                                              lnw, lnb, outp);
}

// Round 11
// 227.221 us; speedup vs baseline: 1.0395x; 1.0395x over previous
//
#include <hip/hip_runtime.h>
#include <hip/hip_fp16.h>

constexpr int N_NODES = 50000;
constexpr int N_EDGES = 800000;
constexpr int HIDDEN  = 128;
constexpr float RSQRT_D = 0.17677669529663687f;  // 1/sqrt(32)
constexpr int Y_SIZE = N_NODES * HIDDEN;         // 6,400,000
constexpr int M_PAD  = 50048;                    // 391 * 128
constexpr int SCAN_BLOCKS = 196;                 // 196*256 = 50176 >= N_NODES
constexpr int XCVT_BLOCKS = (M_PAD * 16) / 256;  // 3128
constexpr int HIST_BLOCKS = N_EDGES / 256;       // 3125
constexpr int STAT_BLOCKS = (N_NODES + 31) / 32; // 1563

// ---- ws layout (float offsets) ----
constexpr size_t OFF_Q      = 0;         // fp16 qb
constexpr size_t OFF_K      = 6400000;   // fp16 kv interleaved [node][256]: 25.6 MB
constexpr size_t OFF_S      = 19200000;  // fp16 sb (lower half)
constexpr size_t OFF_EXC    = 22400000;  // E*4 floats: CSR-ordered raw exp (scratch)
constexpr size_t OFF_WT     = 25600000;  // Wt_swz bf16 (dead after k_mm)
constexpr size_t OFF_GSUM   = 25800000;  // 64
constexpr size_t OFF_GSQ    = 25800064;  // 64
constexpr size_t OFF_GCNT   = 25800128;  // 64 ints
constexpr size_t OFF_DEG    = 25800192;  // 50000 ints
constexpr size_t OFF_OFFS   = 25850192;  // 50001 ints
constexpr size_t OFF_CURSOR = 25900224;  // 50000 ints
constexpr size_t OFF_CSR    = 25950224;  // 800000 int2 (packed src,eid) = 1.6M ints
constexpr size_t OFF_PART   = 27550224;  // 196 ints (raw scan partials)

typedef __attribute__((ext_vector_type(8))) short bf16x8;
typedef __attribute__((ext_vector_type(4))) float f32x4;

__device__ __forceinline__ short f2bf(float f) {  // RNE f32 -> bf16 bits
    unsigned u = __float_as_uint(f);
    unsigned r = (u + 0x7fff + ((u >> 16) & 1)) >> 16;
    return (short)r;
}

__device__ __forceinline__ void gload_lds16(const void* g, void* l) {
    __builtin_amdgcn_global_load_lds(
        (const __attribute__((address_space(1))) void*)g,
        (__attribute__((address_space(3))) void*)l, 16, 0, 0);
}

// ---------------- prep: x->bf16 swizzled | W->Wt bf16 swizzled | degree hist ----------------
__global__ __launch_bounds__(256) void k_prep(
    const float* __restrict__ x,
    const float* __restrict__ Wq, const float* __restrict__ Wk,
    const float* __restrict__ Wv, const float* __restrict__ Wsm,
    const int* __restrict__ dst,
    short* __restrict__ xs, short* __restrict__ wt, int* __restrict__ deg)
{
    int b = blockIdx.x;
    if (b < XCVT_BLOCKS) {
        int tid = b * 256 + threadIdx.x;  // M_PAD*16 exact
        int row = tid >> 4, ci = tid & 15;
        short o[8];
        if (row < N_NODES) {
            float4 a = *(const float4*)&x[(size_t)row * 128 + ci * 8];
            float4 bb = *(const float4*)&x[(size_t)row * 128 + ci * 8 + 4];
            o[0] = f2bf(a.x); o[1] = f2bf(a.y); o[2] = f2bf(a.z); o[3] = f2bf(a.w);
            o[4] = f2bf(bb.x); o[5] = f2bf(bb.y); o[6] = f2bf(bb.z); o[7] = f2bf(bb.w);
        } else {
            #pragma unroll
            for (int j = 0; j < 8; ++j) o[j] = 0;
        }
        int cs = ci ^ (row & 7);
        *(int4*)&xs[(size_t)row * 128 + cs * 8] = *(int4*)o;
    } else if (b < XCVT_BLOCKS + 32) {
        int tid = (b - XCVT_BLOCKS) * 256 + threadIdx.x;  // 8192 exact
        int mat = tid >> 11, n = (tid >> 4) & 127, kg = tid & 15;
        const float* W = (mat == 0) ? Wq : (mat == 1) ? Wk : (mat == 2) ? Wv : Wsm;
        short o[8];
        #pragma unroll
        for (int j = 0; j < 8; ++j) o[j] = f2bf(W[(kg * 8 + j) * 128 + n]);
        int cs = kg ^ (n & 7);
        *(int4*)&wt[mat * 16384 + n * 128 + cs * 8] = *(int4*)o;
    } else {
        int e = (b - XCVT_BLOCKS - 32) * 256 + threadIdx.x;  // E exact
        atomicAdd(&deg[dst[e]], 1);
    }
}

// ---------------- MFMA GEMM, single dispatch: all 4 mats per block ----------------
// A staged once via global_load_lds (bf16, pre-swizzled); B re-staged per mat.
__global__ __launch_bounds__(256) void k_mm(
    const short* __restrict__ xs, const short* __restrict__ wt,
    const float* __restrict__ bq, const float* __restrict__ bk,
    const float* __restrict__ bv, const float* __restrict__ bs,
    __half* __restrict__ qb, __half* __restrict__ kv, __half* __restrict__ sb)
{
    __shared__ __align__(16) char As[32768];
    __shared__ __align__(16) char Bs[32768];
    const int t = threadIdx.x, lane = t & 63, wv = t >> 6;
    const int m0 = blockIdx.x * 128;
    const int wm = wv >> 1, wn = wv & 1;

    const char* gA = (const char*)xs + (size_t)m0 * 256;
    #pragma unroll
    for (int i = 0; i < 8; ++i) {
        int chunk = wv * 8 + i;
        gload_lds16(gA + chunk * 1024 + lane * 16, As + chunk * 1024);
        gload_lds16((const char*)wt + chunk * 1024 + lane * 16, Bs + chunk * 1024);
    }
    __syncthreads();

    bf16x8 af[4][4];  // [ks][mf], same A for all mats
    #pragma unroll
    for (int ks = 0; ks < 4; ++ks) {
        const int cbase = ks * 64 + ((lane >> 4) << 4);
        #pragma unroll
        for (int mf = 0; mf < 4; ++mf) {
            int mr = wm * 64 + mf * 16 + (lane & 15);
            af[ks][mf] = *(const bf16x8*)(As + mr * 256 + (cbase ^ ((mr & 7) << 4)));
        }
    }

    const float* Bbs[4] = {bq, bk, bv, bs};
    #pragma unroll
    for (int mat = 0; mat < 4; ++mat) {
        f32x4 acc[4][4];
        #pragma unroll
        for (int nf = 0; nf < 4; ++nf) {
            float bc = Bbs[mat][wn * 64 + nf * 16 + (lane & 15)];
            #pragma unroll
            for (int mf = 0; mf < 4; ++mf) acc[mf][nf] = (f32x4){bc, bc, bc, bc};
        }
        #pragma unroll
        for (int ks = 0; ks < 4; ++ks) {
            bf16x8 bfr[4];
            const int cbase = ks * 64 + ((lane >> 4) << 4);
            #pragma unroll
            for (int nf = 0; nf < 4; ++nf) {
                int nc = wn * 64 + nf * 16 + (lane & 15);
                bfr[nf] = *(const bf16x8*)(Bs + nc * 256 + (cbase ^ ((nc & 7) << 4)));
            }
            #pragma unroll
            for (int mf = 0; mf < 4; ++mf)
                #pragma unroll
                for (int nf = 0; nf < 4; ++nf)
                    acc[mf][nf] = __builtin_amdgcn_mfma_f32_16x16x32_bf16(
                        af[ks][mf], bfr[nf], acc[mf][nf], 0, 0, 0);
        }
        __syncthreads();  // all waves done reading Bs
        if (mat < 3) {    // stage next mat's B while we write out
            const char* gB = (const char*)wt + (mat + 1) * 32768;
            #pragma unroll
            for (int i = 0; i < 8; ++i) {
                int chunk = wv * 8 + i;
                gload_lds16(gB + chunk * 1024 + lane * 16, Bs + chunk * 1024);
            }
        }
        __half* base = (mat == 0) ? qb : (mat == 1) ? kv : (mat == 2) ? (kv + 128) : sb;
        const int rs = (mat == 1 || mat == 2) ? 256 : 128;
        const int colbase = wn * 64 + (lane & 15);
        #pragma unroll
        for (int mf = 0; mf < 4; ++mf) {
            int rowb = m0 + wm * 64 + mf * 16 + ((lane >> 4) << 2);
            #pragma unroll
            for (int nf = 0; nf < 4; ++nf) {
                int col = colbase + nf * 16;
                #pragma unroll
                for (int r = 0; r < 4; ++r) {
                    int node = rowb + r;
                    if (node < N_NODES)
                        base[(size_t)node * rs + col] = __float2half_rn(acc[mf][nf][r]);
                }
            }
        }
        __syncthreads();  // staged Bs complete before next mat's reads
    }
}

// ---------------- scan: per-block sums, then fused partial-scan + intra ----------------
__global__ __launch_bounds__(256) void k_scan1(const int* __restrict__ deg,
                                               int* __restrict__ part)
{
    const int t = threadIdx.x;
    int idx = blockIdx.x * 256 + t;
    int v = (idx < N_NODES) ? deg[idx] : 0;
    #pragma unroll
    for (int o = 1; o < 64; o <<= 1) v += __shfl_xor(v, o);
    __shared__ int wsum[4];
    if ((t & 63) == 0) wsum[t >> 6] = v;
    __syncthreads();
    if (t == 0) part[blockIdx.x] = wsum[0] + wsum[1] + wsum[2] + wsum[3];
}

__global__ __launch_bounds__(256) void k_scan3(const int* __restrict__ deg,
                                               const int* __restrict__ part,
                                               int* __restrict__ offs,
                                               int* __restrict__ cursor)
{
    __shared__ int pbuf[256];
    __shared__ int wsum[4];
    const int t = threadIdx.x;
    int pv = (t < SCAN_BLOCKS) ? part[t] : 0;
    pbuf[t] = pv;
    __syncthreads();
    for (int o = 1; o < 256; o <<= 1) {
        int tmp = (t >= o) ? pbuf[t - o] : 0;
        __syncthreads();
        pbuf[t] += tmp;
        __syncthreads();
    }
    const int bbase = (blockIdx.x == 0) ? 0 : pbuf[blockIdx.x - 1];

    const int idx = blockIdx.x * 256 + t;
    const int lane = t & 63, w = t >> 6;
    int v = (idx < N_NODES) ? deg[idx] : 0;
    int inc = v;
    #pragma unroll
    for (int o = 1; o < 64; o <<= 1) {
        int nb = __shfl_up(inc, o);
        if (lane >= o) inc += nb;
    }
    if (lane == 63) wsum[w] = inc;
    __syncthreads();
    int wbase = 0;
    #pragma unroll
    for (int i = 0; i < 4; ++i) if (i < w) wbase += wsum[i];
    int excl = bbase + wbase + inc - v;
    if (idx < N_NODES) {
        offs[idx] = excl;
        cursor[idx] = excl;
    }
    if (idx == 0) offs[N_NODES] = N_EDGES;
}

__global__ __launch_bounds__(256) void k_scatter(
    const int* __restrict__ src, const int* __restrict__ dst,
    int* __restrict__ cursor, int2* __restrict__ csr)
{
    int e = blockIdx.x * 256 + threadIdx.x;  // E exact
    int d = dst[e];
    int p = atomicAdd(&cursor[d], 1);
    csr[p] = make_int2(src[e], e);
}

// ---------------- fused: logits + exp + aggregate + skip + attn normalize ----------------
// One 64-lane wave per dst node; 16 lanes/edge (8 ch/lane), 4 edges per group.
// Raw exp -> exc (sequential, CSR order); epilogue re-reads own slots (L2-hot),
// scales by per-head rdn, and does ONE gathered 16B random write per edge to attn.
__global__ __launch_bounds__(256) void k_fused(
    const __half* __restrict__ qb, const __half* __restrict__ kv,
    const __half* __restrict__ sb,
    const int* __restrict__ offs, const int2* __restrict__ csr,
    float* __restrict__ exc, float* __restrict__ attn,
    float* __restrict__ outb)
{
    const int t = threadIdx.x;
    const int lane = t & 63;
    const int n = blockIdx.x * 4 + (t >> 6);  // grid*4 == N exact
    const int begin = offs[n], end = offs[n + 1];
    const int cl  = lane & 15;   // owns channels [cl*8, cl*8+8)
    const int qtr = lane >> 4;   // edge slot within 4-group
    const int h   = cl >> 2;     // head of this lane's channels

    const __half2* qp = (const __half2*)(qb + (size_t)n * 128 + cl * 8);
    float2 qf[4];
    #pragma unroll
    for (int j = 0; j < 4; ++j) qf[j] = __half22float2(qp[j]);

    float acc[8] = {0.f, 0.f, 0.f, 0.f, 0.f, 0.f, 0.f, 0.f};
    float dsum = 0.f;
    int i = begin;
    for (; i + 8 <= end; i += 8) {  // two 4-edge groups, unguarded
        const int s0 = csr[i + qtr].x;
        const int s1 = csr[i + 4 + qtr].x;
        const __half2* k0 = (const __half2*)(kv + (size_t)s0 * 256 + cl * 8);
        const __half2* k1 = (const __half2*)(kv + (size_t)s1 * 256 + cl * 8);
        __half2 ka[4], kb2[4], va[4], vb2[4];
        #pragma unroll
        for (int j = 0; j < 4; ++j) { ka[j] = k0[j]; va[j] = k0[64 + j]; }
        #pragma unroll
        for (int j = 0; j < 4; ++j) { kb2[j] = k1[j]; vb2[j] = k1[64 + j]; }
        float p0 = 0.f, p1 = 0.f;
        #pragma unroll
        for (int j = 0; j < 4; ++j) {
            float2 f0 = __half22float2(ka[j]), f1 = __half22float2(kb2[j]);
            p0 += qf[j].x * f0.x + qf[j].y * f0.y;
            p1 += qf[j].x * f1.x + qf[j].y * f1.y;
        }
        p0 += __shfl_xor(p0, 1);  p1 += __shfl_xor(p1, 1);
        p0 += __shfl_xor(p0, 2);  p1 += __shfl_xor(p1, 2);
        const float ex0 = __expf(p0 * RSQRT_D);
        const float ex1 = __expf(p1 * RSQRT_D);
        dsum += ex0 + ex1;
        #pragma unroll
        for (int j = 0; j < 4; ++j) {
            float2 f0 = __half22float2(va[j]), f1 = __half22float2(vb2[j]);
            acc[2*j]   += ex0 * f0.x + ex1 * f1.x;
            acc[2*j+1] += ex0 * f0.y + ex1 * f1.y;
        }
        if ((lane & 3) == 0) {
            exc[(i + qtr) * 4 + h]     = ex0;
            exc[(i + 4 + qtr) * 4 + h] = ex1;
        }
    }
    for (; i < end; i += 4) {  // guarded 4-edge tail
        const int eIdx = i + qtr;
        const bool act = eIdx < end;
        const int s0 = csr[act ? eIdx : end - 1].x;
        const __half2* k0 = (const __half2*)(kv + (size_t)s0 * 256 + cl * 8);
        __half2 ka[4], va[4];
        #pragma unroll
        for (int j = 0; j < 4; ++j) { ka[j] = k0[j]; va[j] = k0[64 + j]; }
        float p0 = 0.f;
        #pragma unroll
        for (int j = 0; j < 4; ++j) {
            float2 f0 = __half22float2(ka[j]);
            p0 += qf[j].x * f0.x + qf[j].y * f0.y;
        }
        p0 += __shfl_xor(p0, 1);
        p0 += __shfl_xor(p0, 2);
        const float ex0 = act ? __expf(p0 * RSQRT_D) : 0.f;
        dsum += ex0;
        #pragma unroll
        for (int j = 0; j < 4; ++j) {
            float2 f0 = __half22float2(va[j]);
            acc[2*j]   += ex0 * f0.x;
            acc[2*j+1] += ex0 * f0.y;
        }
        if (((lane & 3) == 0) && act) exc[eIdx * 4 + h] = ex0;
    }
    // combine the 4 edge-quarters (lanes l, l+16, l+32, l+48 share channels)
    dsum += __shfl_xor(dsum, 16);
    dsum += __shfl_xor(dsum, 32);
    #pragma unroll
    for (int j = 0; j < 8; ++j) {
        acc[j] += __shfl_xor(acc[j], 16);
        acc[j] += __shfl_xor(acc[j], 32);
    }
    // per-head reciprocal denominators, broadcast to every lane
    const float rd0 = 1.f / (__shfl(dsum, 0)  + 1e-16f);
    const float rd1 = 1.f / (__shfl(dsum, 4)  + 1e-16f);
    const float rd2 = 1.f / (__shfl(dsum, 8)  + 1e-16f);
    const float rd3 = 1.f / (__shfl(dsum, 12) + 1e-16f);

    if (lane < 16) {
        const float rdn = 1.f / (dsum + 1e-16f);
        const __half2* sp = (const __half2*)(sb + (size_t)n * 128 + cl * 8);
        float o[8];
        #pragma unroll
        for (int j = 0; j < 4; ++j) {
            float2 sf = __half22float2(sp[j]);
            o[2*j]   = acc[2*j]   * rdn + sf.x;
            o[2*j+1] = acc[2*j+1] * rdn + sf.y;
        }
        *(float4*)&outb[(size_t)n * 128 + cl * 8]     = make_float4(o[0], o[1], o[2], o[3]);
        *(float4*)&outb[(size_t)n * 128 + cl * 8 + 4] = make_float4(o[4], o[5], o[6], o[7]);
    }

    // normalize this node's attn slots: 1 edge/lane, gathered 16B random write
    for (int slot = begin + lane; slot < end; slot += 64) {
        const int eid = csr[slot].y;
        float4 e4 = *(const float4*)&exc[slot * 4];
        ((float4*)attn)[eid] = make_float4(e4.x * rd0, e4.y * rd1,
                                           e4.z * rd2, e4.w * rd3);
    }
}

// ---------------- per-graph sum + sumsq + count, one pass ----------------
__global__ __launch_bounds__(256) void k_stats(
    const float* __restrict__ out, const int* __restrict__ batch,
    float* __restrict__ gsum, float* __restrict__ gsq, int* __restrict__ gcnt)
{
    __shared__ float nsum[32], nsq[32];
    __shared__ int   ngr[32];
    const int t = threadIdx.x;
    const int nl = t >> 3, part = t & 7;
    const int n = blockIdx.x * 32 + nl;
    float lsum = 0.f, lsq = 0.f;
    if (n < N_NODES) {
        size_t base = (size_t)n * 128 + part * 16;
        #pragma unroll
        for (int i = 0; i < 4; ++i) {
            float4 o = *(const float4*)&out[base + i * 4];
            lsum += o.x + o.y + o.z + o.w;
            lsq  += o.x * o.x + o.y * o.y + o.z * o.z + o.w * o.w;
        }
    }
    #pragma unroll
    for (int o = 1; o < 8; o <<= 1) {
        lsum += __shfl_xor(lsum, o);
        lsq  += __shfl_xor(lsq, o);
    }
    if (part == 0) { nsum[nl] = lsum; nsq[nl] = lsq; ngr[nl] = (n < N_NODES) ? batch[n] : -1; }
    __syncthreads();
    if (t == 0) {
        float acc = 0.f, accq = 0.f; int cg = ngr[0], cnt = 0;
        for (int i = 0; i < 32; ++i) {
            int g = ngr[i];
            if (g != cg) {
                if (cg >= 0) { atomicAdd(&gsum[cg], acc); atomicAdd(&gsq[cg], accq);
                               atomicAdd(&gcnt[cg], cnt); }
                acc = 0.f; accq = 0.f; cnt = 0; cg = g;
            }
            acc += nsum[i]; accq += nsq[i]; ++cnt;
        }
        if (cg >= 0) { atomicAdd(&gsum[cg], acc); atomicAdd(&gsq[cg], accq);
                       atomicAdd(&gcnt[cg], cnt); }
    }
}

// ---------------- LayerNorm affine + LeakyReLU (in-place) ----------------
__global__ __launch_bounds__(256) void k_final(
    const float* __restrict__ out, const int* __restrict__ batch,
    const float* __restrict__ gsum, const float* __restrict__ gsq,
    const int* __restrict__ gcnt,
    const float* __restrict__ lnw, const float* __restrict__ lnb,
    float* __restrict__ y)
{
    int idx = blockIdx.x * 256 + threadIdx.x;  // N*128 exact
    int n = idx >> 7, c = idx & 127;
    int g = batch[n];
    float norm = fmaxf((float)gcnt[g], 1.f) * 128.f;
    float mean = gsum[g] / norm;
    float var  = gsq[g] / norm - mean * mean;
    float inv  = rsqrtf(var + 1e-5f);
    float val  = (out[idx] - mean) * inv * lnw[c] + lnb[c];
    y[idx] = val > 0.f ? val : 0.01f * val;
}

extern "C" void kernel_launch(void* const* d_in, const int* in_sizes, int n_in,
                              void* d_out, int out_size, void* d_ws, size_t ws_size,
                              hipStream_t stream)
{
    (void)in_sizes; (void)n_in; (void)out_size; (void)ws_size;
    const float* x    = (const float*)d_in[0];
    const int*   ei   = (const int*)  d_in[1];
    const int*   batch= (const int*)  d_in[2];
    const float* Wq   = (const float*)d_in[3];
    const float* bq   = (const float*)d_in[4];
    const float* Wk   = (const float*)d_in[5];
    const float* bk   = (const float*)d_in[6];
    const float* Wv   = (const float*)d_in[7];
    const float* bv   = (const float*)d_in[8];
    const float* Wsm  = (const float*)d_in[9];
    const float* bs   = (const float*)d_in[10];
    const float* lnw  = (const float*)d_in[11];
    const float* lnb  = (const float*)d_in[12];

    float* outp = (float*)d_out;
    float* ws   = (float*)d_ws;

    const int* srcI = ei;
    const int* dstI = ei + N_EDGES;

    __half* qb      = (__half*)(ws + OFF_Q);
    __half* kv      = (__half*)(ws + OFF_K);
    __half* sb      = (__half*)(ws + OFF_S);
    float*  exc     = ws + OFF_EXC;
    short*  wt      = (short*)(ws + OFF_WT);
    float*  gsum    = ws + OFF_GSUM;
    float*  gsq     = ws + OFF_GSQ;
    int*    gcnt    = (int*)(ws + OFF_GCNT);
    int*    deg     = (int*)(ws + OFF_DEG);
    int*    offs    = (int*)(ws + OFF_OFFS);
    int*    cursor  = (int*)(ws + OFF_CURSOR);
    int2*   csr     = (int2*)(ws + OFF_CSR);
    int*    partArr = (int*)(ws + OFF_PART);

    float* outb  = outp;                  // y region: x_swz first, then pre-LN out
    short* x_swz = (short*)outp;          // 12.8 MB, dead once k_mm finishes
    float* attn  = outp + Y_SIZE;

    // zero gsum/gsq/gcnt + deg (contiguous)
    hipMemsetAsync(gsum, 0, (size_t)(192 + N_NODES) * sizeof(float), stream);

    k_prep<<<XCVT_BLOCKS + 32 + HIST_BLOCKS, 256, 0, stream>>>(
        x, Wq, Wk, Wv, Wsm, dstI, x_swz, wt, deg);
    k_mm<<<M_PAD / 128, 256, 0, stream>>>(x_swz, wt, bq, bk, bv, bs, qb, kv, sb);

    k_scan1<<<SCAN_BLOCKS, 256, 0, stream>>>(deg, partArr);
    k_scan3<<<SCAN_BLOCKS, 256, 0, stream>>>(deg, partArr, offs, cursor);
    k_scatter<<<N_EDGES / 256, 256, 0, stream>>>(srcI, dstI, cursor, csr);
    k_fused<<<N_NODES / 4, 256, 0, stream>>>(qb, kv, sb, offs, csr,
                                             exc, attn, outb);
    k_stats<<<STAT_BLOCKS, 256, 0, stream>>>(outb, batch, gsum, gsq, gcnt);
    k_final<<<Y_SIZE / 256, 256, 0, stream>>>(outb, batch, gsum, gsq, gcnt,
                                              lnw, lnb, outp);
}